// Round 1
// baseline (4343.085 us; speedup 1.0000x reference)
//
#include <hip/hip_runtime.h>

#define Bn 4
#define Tn 1024
#define Cn 768
#define Hn 12
#define Dn 4
#define Vn 32000
#define BTn (Bn*Tn)

typedef __attribute__((ext_vector_type(8))) short short8;
typedef __attribute__((ext_vector_type(4))) float f32x4;

__device__ __forceinline__ unsigned short f2bf(float f) {
  union { float f; unsigned u; } v; v.f = f;
  unsigned r = v.u + 0x7fffu + ((v.u >> 16) & 1u);
  return (unsigned short)(r >> 16);
}

// ---------------- transpose fp32 [K][N] -> bf16 [N][K] ----------------
__global__ __launch_bounds__(256)
void transpose_bf16_kernel(const float* __restrict__ src, unsigned short* __restrict__ dst,
                           int K, int N) {
  __shared__ float tile[32][33];
  const int tx = threadIdx.x, ty = threadIdx.y;
  const int n0 = blockIdx.x * 32, k0 = blockIdx.y * 32;
#pragma unroll
  for (int i = 0; i < 4; ++i)
    tile[ty + i*8][tx] = src[(size_t)(k0 + ty + i*8) * N + n0 + tx];
  __syncthreads();
#pragma unroll
  for (int i = 0; i < 4; ++i)
    dst[(size_t)(n0 + ty + i*8) * K + k0 + tx] = f2bf(tile[tx][ty + i*8]);
}

// ---------------- embedding: h = wordemb[x] + posemb[t], + bf16 copy ----------------
__global__ __launch_bounds__(256)
void embed_kernel(const int* __restrict__ x, const float* __restrict__ wordemb,
                  const float* __restrict__ posemb, float* __restrict__ h,
                  unsigned short* __restrict__ hb) {
  int i4 = blockIdx.x * 256 + threadIdx.x;        // over BTn*Cn/4, exact grid
  int row = i4 / (Cn/4), c4 = i4 % (Cn/4);
  int t = row & (Tn - 1);
  int tok = x[row];
  float4 a = ((const float4*)wordemb)[(size_t)tok * (Cn/4) + c4];
  float4 p = ((const float4*)posemb)[(size_t)t * (Cn/4) + c4];
  float4 s; s.x = a.x+p.x; s.y = a.y+p.y; s.z = a.z+p.z; s.w = a.w+p.w;
  ((float4*)h)[i4] = s;
  ushort4 u; u.x = f2bf(s.x); u.y = f2bf(s.y); u.z = f2bf(s.z); u.w = f2bf(s.w);
  ((ushort4*)hb)[i4] = u;
}

// ---------------- bf16 MFMA GEMM: C[M,N] = A[M,K] * Bt[N,K]^T (+bias, +relu) ----------
// 128x128 tile, BK=32, 256 threads = 4 waves (2x2), each wave 64x64 = 4x4 MFMA frags.
__global__ __launch_bounds__(256)
void gemm_bf16_kernel(const unsigned short* __restrict__ A, const unsigned short* __restrict__ Bt,
                      const float* __restrict__ bias, float* __restrict__ Cf,
                      unsigned short* __restrict__ Cb, int M, int N, int K, int relu) {
  __shared__ unsigned short As[128][40];   // +8 pad: fragment reads 2-way (free)
  __shared__ unsigned short Bs[128][40];
  const int t = threadIdx.x;
  const int bx = blockIdx.x, by = blockIdx.y;
  const int sr = t >> 2, sk = (t & 3) << 3;   // staging: row 0..63, k-chunk of 8
  const int lane = t & 63, w = t >> 6;
  const int wr = w >> 1, wc = w & 1;
  const int lr = lane & 15, lq = lane >> 4;

  f32x4 acc[4][4];
#pragma unroll
  for (int i = 0; i < 4; ++i)
#pragma unroll
    for (int j = 0; j < 4; ++j)
      acc[i][j] = (f32x4){0.f, 0.f, 0.f, 0.f};

  const unsigned short* a0 = A  + (size_t)(by*128 + sr) * K + sk;
  const unsigned short* a1 = a0 + (size_t)64 * K;
  const unsigned short* b0 = Bt + (size_t)(bx*128 + sr) * K + sk;
  const unsigned short* b1 = b0 + (size_t)64 * K;

  for (int k0 = 0; k0 < K; k0 += 32) {
    __syncthreads();
    *(short8*)&As[sr][sk]      = *(const short8*)(a0 + k0);
    *(short8*)&As[sr + 64][sk] = *(const short8*)(a1 + k0);
    *(short8*)&Bs[sr][sk]      = *(const short8*)(b0 + k0);
    *(short8*)&Bs[sr + 64][sk] = *(const short8*)(b1 + k0);
    __syncthreads();
    short8 af[4], bfr[4];
#pragma unroll
    for (int i = 0; i < 4; ++i) af[i]  = *(const short8*)&As[wr*64 + i*16 + lr][lq*8];
#pragma unroll
    for (int j = 0; j < 4; ++j) bfr[j] = *(const short8*)&Bs[wc*64 + j*16 + lr][lq*8];
#pragma unroll
    for (int i = 0; i < 4; ++i)
#pragma unroll
      for (int j = 0; j < 4; ++j)
        acc[i][j] = __builtin_amdgcn_mfma_f32_16x16x32_bf16(af[i], bfr[j], acc[i][j], 0, 0, 0);
  }

#pragma unroll
  for (int i = 0; i < 4; ++i)
#pragma unroll
    for (int j = 0; j < 4; ++j)
#pragma unroll
      for (int r = 0; r < 4; ++r) {
        int grow = by*128 + wr*64 + i*16 + lq*4 + r;   // C/D: row=(lane>>4)*4+reg
        int gcol = bx*128 + wc*64 + j*16 + lr;         //      col=lane&15
        float v = acc[i][j][r];
        if (bias) v += bias[gcol];
        if (relu) v = fmaxf(v, 0.f);
        size_t idx = (size_t)grow * N + gcol;
        if (Cf) Cf[idx] = v;
        if (Cb) Cb[idx] = f2bf(v);
      }
}

// ---------------- flash attention fp32; qkv interleaved [BT][2304]; out bf16 --------
__global__ __launch_bounds__(256)
void attn_kernel(const float* __restrict__ qkv, unsigned short* __restrict__ attb) {
  const int qb = blockIdx.x, hh = blockIdx.y, b = blockIdx.z;
  const int tid = threadIdx.x;
  const int r = tid >> 2, sub = tid & 3;   // 4 threads per q-row, each owns 16 out dims
  const int gq = qb*64 + r;
  __shared__ float Ks[64][68];
  __shared__ float Vs[64][68];
  __shared__ float Ss[64][68];
  const float scale = 0.03608439182435161f;   // 1/sqrt(768): ref scales by sqrt(C)!

  float4 qv[16];
  const float* qrow = qkv + (size_t)(b*Tn + gq) * 2304 + hh*64;
#pragma unroll
  for (int d4 = 0; d4 < 16; ++d4) qv[d4] = *(const float4*)(qrow + d4*4);

  float ox[16];
#pragma unroll
  for (int i = 0; i < 16; ++i) ox[i] = 0.f;
  float m_run = -1e30f, l_run = 0.f;
  const int schunk = sub * 16;

  for (int kb = 0; kb <= qb; ++kb) {
    __syncthreads();
    const float* krow = qkv + (size_t)(b*Tn + kb*64 + r) * 2304 + 768 + hh*64 + schunk;
    const float* vrow = krow + 768;
#pragma unroll
    for (int j = 0; j < 4; ++j) {
      *(float4*)&Ks[r][schunk + j*4] = *(const float4*)(krow + j*4);
      *(float4*)&Vs[r][schunk + j*4] = *(const float4*)(vrow + j*4);
    }
    __syncthreads();
#pragma unroll
    for (int kk = 0; kk < 16; ++kk) {
      int k = schunk + kk;
      float acc = 0.f;
#pragma unroll
      for (int d4 = 0; d4 < 16; ++d4) {
        float4 kv = *(const float4*)&Ks[k][d4*4];
        acc += qv[d4].x*kv.x + qv[d4].y*kv.y + qv[d4].z*kv.z + qv[d4].w*kv.w;
      }
      int gk = kb*64 + k;
      Ss[r][k] = (gk <= gq) ? acc * scale : -1e30f;
    }
    __syncthreads();
    float mrow = -1e30f;
#pragma unroll 8
    for (int k = 0; k < 64; ++k) mrow = fmaxf(mrow, Ss[r][k]);
    float mn = fmaxf(m_run, mrow);
    float corr = __expf(m_run - mn);
    l_run *= corr;
#pragma unroll
    for (int i = 0; i < 16; ++i) ox[i] *= corr;
    float lsum = 0.f;
    for (int k = 0; k < 64; ++k) {
      float p = __expf(Ss[r][k] - mn);
      lsum += p;
#pragma unroll
      for (int j = 0; j < 4; ++j) {
        float4 vv = *(const float4*)&Vs[k][schunk + j*4];
        ox[j*4+0] += p*vv.x; ox[j*4+1] += p*vv.y; ox[j*4+2] += p*vv.z; ox[j*4+3] += p*vv.w;
      }
    }
    l_run += lsum;
    m_run = mn;
  }
  float inv = 1.f / l_run;
  unsigned short* orow = attb + (size_t)(b*Tn + gq) * 768 + hh*64 + schunk;
#pragma unroll
  for (int j = 0; j < 4; ++j) {
    ushort4 u;
    u.x = f2bf(ox[j*4+0]*inv); u.y = f2bf(ox[j*4+1]*inv);
    u.z = f2bf(ox[j*4+2]*inv); u.w = f2bf(ox[j*4+3]*inv);
    *(ushort4*)(orow + j*4) = u;
  }
}

// ---------------- residual + layernorm: h = h + LN(x)*g+b ; also bf16 copy ----------
__global__ __launch_bounds__(256)
void ln_res_kernel(const float* __restrict__ x, float* __restrict__ h,
                   unsigned short* __restrict__ hb, const float* __restrict__ g,
                   const float* __restrict__ bb) {
  const int row = blockIdx.x, tid = threadIdx.x;
  const float* xr = x + (size_t)row * Cn;
  float v[3], s1 = 0.f, s2 = 0.f;
#pragma unroll
  for (int j = 0; j < 3; ++j) { v[j] = xr[tid + j*256]; s1 += v[j]; s2 += v[j]*v[j]; }
  __shared__ float r1[256], r2[256];
  r1[tid] = s1; r2[tid] = s2;
  __syncthreads();
  for (int s = 128; s > 0; s >>= 1) {
    if (tid < s) { r1[tid] += r1[tid+s]; r2[tid] += r2[tid+s]; }
    __syncthreads();
  }
  float mu = r1[0] * (1.f/768.f);
  float var = r2[0] * (1.f/768.f) - mu*mu;
  float rs = rsqrtf(var + 1e-5f);
  float* hr = h + (size_t)row * Cn;
  unsigned short* hbr = hb + (size_t)row * Cn;
#pragma unroll
  for (int j = 0; j < 3; ++j) {
    int c = tid + j*256;
    float y = hr[c] + (v[j]-mu)*rs*g[c] + bb[c];
    hr[c] = y;
    hbr[c] = f2bf(y);
  }
}

// ---------------- loss: per-row logsumexp - logit[y], then deterministic mean -------
__global__ __launch_bounds__(256)
void loss_row_kernel(const float* __restrict__ logits, const int* __restrict__ y,
                     float* __restrict__ loss_rows) {
  const int row = blockIdx.x, tid = threadIdx.x;
  const float* lg = logits + (size_t)row * Vn;
  __shared__ float red[256];
  float mx = -1e30f;
  for (int j = 0; j < Vn/256; ++j) mx = fmaxf(mx, lg[tid + j*256]);
  red[tid] = mx; __syncthreads();
  for (int s = 128; s > 0; s >>= 1) {
    if (tid < s) red[tid] = fmaxf(red[tid], red[tid+s]);
    __syncthreads();
  }
  mx = red[0]; __syncthreads();
  float sum = 0.f;
  for (int j = 0; j < Vn/256; ++j) sum += __expf(lg[tid + j*256] - mx);
  red[tid] = sum; __syncthreads();
  for (int s = 128; s > 0; s >>= 1) {
    if (tid < s) red[tid] += red[tid+s];
    __syncthreads();
  }
  if (tid == 0) {
    float lse = mx + __logf(red[0]);
    loss_rows[row] = lse - lg[y[row]];
  }
}

__global__ __launch_bounds__(256)
void loss_reduce_kernel(const float* __restrict__ loss_rows, float* __restrict__ out) {
  const int tid = threadIdx.x;
  float s = 0.f;
  for (int j = 0; j < BTn/256; ++j) s += loss_rows[tid + j*256];
  __shared__ float red[256];
  red[tid] = s; __syncthreads();
  for (int st = 128; st > 0; st >>= 1) {
    if (tid < st) red[tid] += red[tid+st];
    __syncthreads();
  }
  if (tid == 0) out[0] = red[0] * (1.f/(float)BTn);
}

// =====================================================================================
extern "C" void kernel_launch(void* const* d_in, const int* in_sizes, int n_in,
                              void* d_out, int out_size, void* d_ws, size_t ws_size,
                              hipStream_t stream) {
  const int*   x       = (const int*)  d_in[0];
  const int*   y       = (const int*)  d_in[1];
  const float* wordemb = (const float*)d_in[2];
  const float* posemb  = (const float*)d_in[3];
  const float* Wq      = (const float*)d_in[4];
  const float* Wk      = (const float*)d_in[5];
  const float* Wv      = (const float*)d_in[6];
  const float* Wo      = (const float*)d_in[7];
  const float* bo      = (const float*)d_in[8];
  const float* ln1_g   = (const float*)d_in[9];
  const float* ln1_b   = (const float*)d_in[10];
  const float* W1      = (const float*)d_in[11];
  const float* b1      = (const float*)d_in[12];
  const float* W2      = (const float*)d_in[13];
  const float* b2      = (const float*)d_in[14];
  const float* ln2_g   = (const float*)d_in[15];
  const float* ln2_b   = (const float*)d_in[16];
  const float* Wl      = (const float*)d_in[17];
  const float* bl      = (const float*)d_in[18];

  char* ws = (char*)d_ws;
  size_t off = 0;
  auto alloc = [&](size_t bytes) -> char* {
    char* p = ws + off;
    off += (bytes + 255) & ~(size_t)255;
    return p;
  };
  unsigned short* wqkvT = (unsigned short*)alloc((size_t)Dn*2304*768*2);
  unsigned short* woT   = (unsigned short*)alloc((size_t)Dn*768*768*2);
  unsigned short* w1T   = (unsigned short*)alloc((size_t)Dn*3072*768*2);
  unsigned short* w2T   = (unsigned short*)alloc((size_t)Dn*768*3072*2);
  unsigned short* wlT   = (unsigned short*)alloc((size_t)Vn*768*2);
  float*          h     = (float*)alloc((size_t)BTn*Cn*4);
  unsigned short* hb    = (unsigned short*)alloc((size_t)BTn*Cn*2);
  float*          qkv   = (float*)alloc((size_t)BTn*2304*4);
  unsigned short* attb  = (unsigned short*)alloc((size_t)BTn*Cn*2);
  float*          tmp   = (float*)alloc((size_t)BTn*Cn*4);       // attout / ff2
  float*          loss_rows = (float*)alloc((size_t)BTn*4);
  unsigned short* ff1b  = (unsigned short*)qkv;  // alias: qkv dead once attn done

  dim3 tb(32, 8);
  for (int d = 0; d < Dn; ++d) {
    transpose_bf16_kernel<<<dim3(24,24), tb, 0, stream>>>(Wq + (size_t)d*Cn*Cn, wqkvT + (size_t)d*2304*768,            Cn, Cn);
    transpose_bf16_kernel<<<dim3(24,24), tb, 0, stream>>>(Wk + (size_t)d*Cn*Cn, wqkvT + (size_t)d*2304*768 + 768*768,  Cn, Cn);
    transpose_bf16_kernel<<<dim3(24,24), tb, 0, stream>>>(Wv + (size_t)d*Cn*Cn, wqkvT + (size_t)d*2304*768 + 1536*768, Cn, Cn);
    transpose_bf16_kernel<<<dim3(24,24), tb, 0, stream>>>(Wo + (size_t)d*Cn*Cn, woT + (size_t)d*768*768,  Cn, Cn);
    transpose_bf16_kernel<<<dim3(96,24), tb, 0, stream>>>(W1 + (size_t)d*768*3072, w1T + (size_t)d*3072*768, 768, 3072);
    transpose_bf16_kernel<<<dim3(24,96), tb, 0, stream>>>(W2 + (size_t)d*3072*768, w2T + (size_t)d*768*3072, 3072, 768);
  }
  transpose_bf16_kernel<<<dim3(1000,24), tb, 0, stream>>>(Wl, wlT, 768, Vn);

  embed_kernel<<<(BTn*Cn/4)/256, 256, 0, stream>>>(x, wordemb, posemb, h, hb);

  for (int d = 0; d < Dn; ++d) {
    // fused QKV projection: [BT,768] x [768,2304] -> qkv fp32
    gemm_bf16_kernel<<<dim3(2304/128, BTn/128), 256, 0, stream>>>(
        hb, wqkvT + (size_t)d*2304*768, nullptr, qkv, nullptr, BTn, 2304, 768, 0);
    attn_kernel<<<dim3(Tn/64, Hn, Bn), 256, 0, stream>>>(qkv, attb);
    gemm_bf16_kernel<<<dim3(768/128, BTn/128), 256, 0, stream>>>(
        attb, woT + (size_t)d*768*768, bo + (size_t)d*768, tmp, nullptr, BTn, 768, 768, 0);
    ln_res_kernel<<<BTn, 256, 0, stream>>>(tmp, h, hb, ln1_g + (size_t)d*768, ln1_b + (size_t)d*768);
    gemm_bf16_kernel<<<dim3(3072/128, BTn/128), 256, 0, stream>>>(
        hb, w1T + (size_t)d*3072*768, b1 + (size_t)d*3072, nullptr, ff1b, BTn, 3072, 768, 1);
    gemm_bf16_kernel<<<dim3(768/128, BTn/128), 256, 0, stream>>>(
        ff1b, w2T + (size_t)d*768*3072, b2 + (size_t)d*768, tmp, nullptr, BTn, 768, 3072, 0);
    ln_res_kernel<<<BTn, 256, 0, stream>>>(tmp, h, hb, ln2_g + (size_t)d*768, ln2_b + (size_t)d*768);
  }

  float* logits = (float*)d_out;
  gemm_bf16_kernel<<<dim3(Vn/128, BTn/128), 256, 0, stream>>>(
      hb, wlT, bl, logits, nullptr, BTn, Vn, 768, 0);
  loss_row_kernel<<<BTn, 256, 0, stream>>>(logits, y, loss_rows);
  loss_reduce_kernel<<<1, 256, 0, stream>>>(loss_rows, logits + (size_t)BTn*Vn);
}

// Round 2
// 1831.641 us; speedup vs baseline: 2.3711x; 2.3711x over previous
//
#include <hip/hip_runtime.h>

#define Bn 4
#define Tn 1024
#define Cn 768
#define Hn 12
#define Dn 4
#define Vn 32000
#define BTn (Bn*Tn)

typedef __attribute__((ext_vector_type(8))) short short8;
typedef __attribute__((ext_vector_type(4))) float f32x4;

__device__ __forceinline__ unsigned short f2bf(float f) {
  union { float f; unsigned u; } v; v.f = f;
  unsigned r = v.u + 0x7fffu + ((v.u >> 16) & 1u);
  return (unsigned short)(r >> 16);
}

// ---------------- transpose fp32 [K][N] -> bf16 [N][K] ----------------
__global__ __launch_bounds__(256)
void transpose_bf16_kernel(const float* __restrict__ src, unsigned short* __restrict__ dst,
                           int K, int N) {
  __shared__ float tile[32][33];
  const int tx = threadIdx.x, ty = threadIdx.y;
  const int n0 = blockIdx.x * 32, k0 = blockIdx.y * 32;
#pragma unroll
  for (int i = 0; i < 4; ++i)
    tile[ty + i*8][tx] = src[(size_t)(k0 + ty + i*8) * N + n0 + tx];
  __syncthreads();
#pragma unroll
  for (int i = 0; i < 4; ++i)
    dst[(size_t)(n0 + ty + i*8) * K + k0 + tx] = f2bf(tile[tx][ty + i*8]);
}

// ---------------- embedding: h = wordemb[x] + posemb[t], + bf16 copy ----------------
__global__ __launch_bounds__(256)
void embed_kernel(const int* __restrict__ x, const float* __restrict__ wordemb,
                  const float* __restrict__ posemb, float* __restrict__ h,
                  unsigned short* __restrict__ hb) {
  int i4 = blockIdx.x * 256 + threadIdx.x;        // over BTn*Cn/4, exact grid
  int row = i4 / (Cn/4), c4 = i4 % (Cn/4);
  int t = row & (Tn - 1);
  int tok = x[row];
  float4 a = ((const float4*)wordemb)[(size_t)tok * (Cn/4) + c4];
  float4 p = ((const float4*)posemb)[(size_t)t * (Cn/4) + c4];
  float4 s; s.x = a.x+p.x; s.y = a.y+p.y; s.z = a.z+p.z; s.w = a.w+p.w;
  ((float4*)h)[i4] = s;
  ushort4 u; u.x = f2bf(s.x); u.y = f2bf(s.y); u.z = f2bf(s.z); u.w = f2bf(s.w);
  ((ushort4*)hb)[i4] = u;
}

// ---------------- bf16 MFMA GEMM: C[M,N] = A[M,K] * Bt[N,K]^T (+bias, +relu) ----------
__global__ __launch_bounds__(256)
void gemm_bf16_kernel(const unsigned short* __restrict__ A, const unsigned short* __restrict__ Bt,
                      const float* __restrict__ bias, float* __restrict__ Cf,
                      unsigned short* __restrict__ Cb, int M, int N, int K, int relu) {
  __shared__ unsigned short As[128][40];   // +8 pad: fragment reads 2-way (free)
  __shared__ unsigned short Bs[128][40];
  const int t = threadIdx.x;
  const int bx = blockIdx.x, by = blockIdx.y;
  const int sr = t >> 2, sk = (t & 3) << 3;   // staging: row 0..63, k-chunk of 8
  const int lane = t & 63, w = t >> 6;
  const int wr = w >> 1, wc = w & 1;
  const int lr = lane & 15, lq = lane >> 4;

  f32x4 acc[4][4];
#pragma unroll
  for (int i = 0; i < 4; ++i)
#pragma unroll
    for (int j = 0; j < 4; ++j)
      acc[i][j] = (f32x4){0.f, 0.f, 0.f, 0.f};

  const unsigned short* a0 = A  + (size_t)(by*128 + sr) * K + sk;
  const unsigned short* a1 = a0 + (size_t)64 * K;
  const unsigned short* b0 = Bt + (size_t)(bx*128 + sr) * K + sk;
  const unsigned short* b1 = b0 + (size_t)64 * K;

  for (int k0 = 0; k0 < K; k0 += 32) {
    __syncthreads();
    *(short8*)&As[sr][sk]      = *(const short8*)(a0 + k0);
    *(short8*)&As[sr + 64][sk] = *(const short8*)(a1 + k0);
    *(short8*)&Bs[sr][sk]      = *(const short8*)(b0 + k0);
    *(short8*)&Bs[sr + 64][sk] = *(const short8*)(b1 + k0);
    __syncthreads();
    short8 af[4], bfr[4];
#pragma unroll
    for (int i = 0; i < 4; ++i) af[i]  = *(const short8*)&As[wr*64 + i*16 + lr][lq*8];
#pragma unroll
    for (int j = 0; j < 4; ++j) bfr[j] = *(const short8*)&Bs[wc*64 + j*16 + lr][lq*8];
#pragma unroll
    for (int i = 0; i < 4; ++i)
#pragma unroll
      for (int j = 0; j < 4; ++j)
        acc[i][j] = __builtin_amdgcn_mfma_f32_16x16x32_bf16(af[i], bfr[j], acc[i][j], 0, 0, 0);
  }

#pragma unroll
  for (int i = 0; i < 4; ++i)
#pragma unroll
    for (int j = 0; j < 4; ++j)
#pragma unroll
      for (int r = 0; r < 4; ++r) {
        int grow = by*128 + wr*64 + i*16 + lq*4 + r;   // C/D: row=(lane>>4)*4+reg
        int gcol = bx*128 + wc*64 + j*16 + lr;         //      col=lane&15
        float v = acc[i][j][r];
        if (bias) v += bias[gcol];
        if (relu) v = fmaxf(v, 0.f);
        size_t idx = (size_t)grow * N + gcol;
        if (Cf) Cf[idx] = v;
        if (Cb) Cb[idx] = f2bf(v);
      }
}

// ---------------- vT: qkvb V-section [BT][2304] -> vT[b][h][d][t] (bf16) -------------
__global__ __launch_bounds__(256)
void vT_kernel(const unsigned short* __restrict__ qkvb, unsigned short* __restrict__ vT) {
  const int tb = blockIdx.x, hh = blockIdx.y, b = blockIdx.z;
  const int t = threadIdx.x;
  __shared__ unsigned short tile[64][65];
  const int r = t >> 2, c = t & 3;
  const unsigned short* src = qkvb + (size_t)(b*Tn + tb*64 + r) * 2304 + 1536 + hh*64 + c*16;
  short8 v0 = *(const short8*)src;
  short8 v1 = *(const short8*)(src + 8);
#pragma unroll
  for (int j = 0; j < 8; ++j) { tile[r][c*16 + j] = (unsigned short)v0[j]; tile[r][c*16 + 8 + j] = (unsigned short)v1[j]; }
  __syncthreads();
  unsigned short o[16];
#pragma unroll
  for (int j = 0; j < 16; ++j) o[j] = tile[c*16 + j][r];
  unsigned short* dst = vT + ((size_t)((b*Hn + hh)*64 + r)) * Tn + tb*64 + c*16;
  *(ushort4*)(dst)      = *(ushort4*)&o[0];
  *(ushort4*)(dst + 4)  = *(ushort4*)&o[4];
  *(ushort4*)(dst + 8)  = *(ushort4*)&o[8];
  *(ushort4*)(dst + 12) = *(ushort4*)&o[12];
}

// ---------------- MFMA flash attention: bf16 in/out, fp32 accum ----------------------
// block = 4 waves, 64 q-rows; KV tiles of 64 staged in LDS with 16B-slot XOR swizzle.
__global__ __launch_bounds__(256)
void attn_mfma_kernel(const unsigned short* __restrict__ qkvb,
                      const unsigned short* __restrict__ vT,
                      unsigned short* __restrict__ attb) {
  const int qb = blockIdx.x, hh = blockIdx.y, b = blockIdx.z;
  const int t = threadIdx.x;
  const int lane = t & 63, w = t >> 6;
  const int lr = lane & 15, lg = lane >> 4;
  const float scale = 0.03608439182435161f;   // 1/sqrt(768): ref scales by sqrt(C)

  __shared__ unsigned short Ks[64*64];        // [k][64d], slots XOR-swizzled
  __shared__ unsigned short Vs[64*64];        // [d][64k], slots XOR-swizzled
  __shared__ unsigned short Ps[4][16][72];    // per-wave P tile, +8 pad

  // Q fragments (A layout: row=lane&15, k=(lane>>4)*8..): wave w owns q rows w*16..+15
  const unsigned short* qsrc = qkvb + (size_t)(b*Tn + qb*64 + w*16 + lr)*2304 + hh*64 + lg*8;
  short8 qa0 = *(const short8*)(qsrc);
  short8 qa1 = *(const short8*)(qsrc + 32);

  f32x4 acc[4];
#pragma unroll
  for (int dt = 0; dt < 4; ++dt) acc[dt] = (f32x4){0.f,0.f,0.f,0.f};
  float m_run[4], l_run[4];
#pragma unroll
  for (int r = 0; r < 4; ++r) { m_run[r] = -1e30f; l_run[r] = 0.f; }

  const int sr = t >> 2, c2 = t & 3;          // staging: row, 32B chunk

  for (int kvb = 0; kvb <= qb; ++kvb) {
    __syncthreads();
    {
      const unsigned short* ksrc = qkvb + (size_t)(b*Tn + kvb*64 + sr)*2304 + 768 + hh*64 + c2*16;
      short8 k0 = *(const short8*)ksrc;
      short8 k1 = *(const short8*)(ksrc + 8);
      const unsigned short* vsrc = vT + ((size_t)((b*Hn + hh)*64 + sr))*Tn + kvb*64 + c2*16;
      short8 vv0 = *(const short8*)vsrc;
      short8 vv1 = *(const short8*)(vsrc + 8);
      int s0 = (2*c2) ^ (sr & 7), s1 = (2*c2 + 1) ^ (sr & 7);
      *(short8*)&Ks[sr*64 + s0*8] = k0;
      *(short8*)&Ks[sr*64 + s1*8] = k1;
      *(short8*)&Vs[sr*64 + s0*8] = vv0;
      *(short8*)&Vs[sr*64 + s1*8] = vv1;
    }
    __syncthreads();

    // QK^T: S[16q x 64k] per wave
    f32x4 s[4];
#pragma unroll
    for (int kt = 0; kt < 4; ++kt) {
      int krow = kt*16 + lr;
      short8 kf0 = *(const short8*)&Ks[krow*64 + ((0 + lg) ^ (krow & 7))*8];
      short8 kf1 = *(const short8*)&Ks[krow*64 + ((4 + lg) ^ (krow & 7))*8];
      f32x4 a = (f32x4){0.f,0.f,0.f,0.f};
      a = __builtin_amdgcn_mfma_f32_16x16x32_bf16(qa0, kf0, a, 0, 0, 0);
      a = __builtin_amdgcn_mfma_f32_16x16x32_bf16(qa1, kf1, a, 0, 0, 0);
      s[kt] = a;
    }
    // scale + causal mask (only diagonal block partial)
    const bool diag = (kvb == qb);
#pragma unroll
    for (int kt = 0; kt < 4; ++kt)
#pragma unroll
      for (int r = 0; r < 4; ++r) {
        float v = s[kt][r] * scale;
        if (diag && (kt*16 + lr > w*16 + lg*4 + r)) v = -1e30f;
        s[kt][r] = v;
      }
    // online softmax: row = fixed per reg r; 16 k per lane-group, 4 kt tiles
#pragma unroll
    for (int r = 0; r < 4; ++r) {
      float m = fmaxf(fmaxf(s[0][r], s[1][r]), fmaxf(s[2][r], s[3][r]));
      m = fmaxf(m, __shfl_xor(m, 1));
      m = fmaxf(m, __shfl_xor(m, 2));
      m = fmaxf(m, __shfl_xor(m, 4));
      m = fmaxf(m, __shfl_xor(m, 8));
      float mn = fmaxf(m_run[r], m);
      float corr = __expf(m_run[r] - mn);
      m_run[r] = mn;
      float ps = 0.f;
#pragma unroll
      for (int kt = 0; kt < 4; ++kt) {
        float p = __expf(s[kt][r] - mn);
        s[kt][r] = p;
        ps += p;
      }
      ps += __shfl_xor(ps, 1);
      ps += __shfl_xor(ps, 2);
      ps += __shfl_xor(ps, 4);
      ps += __shfl_xor(ps, 8);
      l_run[r] = l_run[r] * corr + ps;
#pragma unroll
      for (int dt = 0; dt < 4; ++dt) acc[dt][r] *= corr;
    }
    // P (C/D layout) -> LDS -> A-layout fragments
#pragma unroll
    for (int kt = 0; kt < 4; ++kt)
#pragma unroll
      for (int r = 0; r < 4; ++r)
        Ps[w][lg*4 + r][kt*16 + lr] = f2bf(s[kt][r]);
    short8 pa0 = *(const short8*)&Ps[w][lr][lg*8];
    short8 pa1 = *(const short8*)&Ps[w][lr][32 + lg*8];
    // PV: O[16q x 64d] += P * V
#pragma unroll
    for (int dt = 0; dt < 4; ++dt) {
      int drow = dt*16 + lr;
      short8 vf0 = *(const short8*)&Vs[drow*64 + ((0 + lg) ^ (drow & 7))*8];
      short8 vf1 = *(const short8*)&Vs[drow*64 + ((4 + lg) ^ (drow & 7))*8];
      acc[dt] = __builtin_amdgcn_mfma_f32_16x16x32_bf16(pa0, vf0, acc[dt], 0, 0, 0);
      acc[dt] = __builtin_amdgcn_mfma_f32_16x16x32_bf16(pa1, vf1, acc[dt], 0, 0, 0);
    }
  }

  unsigned short* obase = attb + (size_t)(b*Tn + qb*64 + w*16)*768 + hh*64;
#pragma unroll
  for (int dt = 0; dt < 4; ++dt)
#pragma unroll
    for (int r = 0; r < 4; ++r) {
      float v = acc[dt][r] / l_run[r];
      obase[(size_t)(lg*4 + r)*768 + dt*16 + lr] = f2bf(v);
    }
}

// ---------------- residual + layernorm: h = h + LN(x)*g+b ; also bf16 copy ----------
__global__ __launch_bounds__(256)
void ln_res_kernel(const float* __restrict__ x, float* __restrict__ h,
                   unsigned short* __restrict__ hb, const float* __restrict__ g,
                   const float* __restrict__ bb) {
  const int row = blockIdx.x, tid = threadIdx.x;
  const float* xr = x + (size_t)row * Cn;
  float v[3], s1 = 0.f, s2 = 0.f;
#pragma unroll
  for (int j = 0; j < 3; ++j) { v[j] = xr[tid + j*256]; s1 += v[j]; s2 += v[j]*v[j]; }
  __shared__ float r1[256], r2[256];
  r1[tid] = s1; r2[tid] = s2;
  __syncthreads();
  for (int s = 128; s > 0; s >>= 1) {
    if (tid < s) { r1[tid] += r1[tid+s]; r2[tid] += r2[tid+s]; }
    __syncthreads();
  }
  float mu = r1[0] * (1.f/768.f);
  float var = r2[0] * (1.f/768.f) - mu*mu;
  float rs = rsqrtf(var + 1e-5f);
  float* hr = h + (size_t)row * Cn;
  unsigned short* hbr = hb + (size_t)row * Cn;
#pragma unroll
  for (int j = 0; j < 3; ++j) {
    int c = tid + j*256;
    float y = hr[c] + (v[j]-mu)*rs*g[c] + bb[c];
    hr[c] = y;
    hbr[c] = f2bf(y);
  }
}

// ---------------- loss: per-row logsumexp - logit[y], then deterministic mean -------
__global__ __launch_bounds__(256)
void loss_row_kernel(const float* __restrict__ logits, const int* __restrict__ y,
                     float* __restrict__ loss_rows) {
  const int row = blockIdx.x, tid = threadIdx.x;
  const float* lg = logits + (size_t)row * Vn;
  __shared__ float red[256];
  float mx = -1e30f;
  for (int j = 0; j < Vn/256; ++j) mx = fmaxf(mx, lg[tid + j*256]);
  red[tid] = mx; __syncthreads();
  for (int s = 128; s > 0; s >>= 1) {
    if (tid < s) red[tid] = fmaxf(red[tid], red[tid+s]);
    __syncthreads();
  }
  mx = red[0]; __syncthreads();
  float sum = 0.f;
  for (int j = 0; j < Vn/256; ++j) sum += __expf(lg[tid + j*256] - mx);
  red[tid] = sum; __syncthreads();
  for (int s = 128; s > 0; s >>= 1) {
    if (tid < s) red[tid] += red[tid+s];
    __syncthreads();
  }
  if (tid == 0) {
    float lse = mx + __logf(red[0]);
    loss_rows[row] = lse - lg[y[row]];
  }
}

__global__ __launch_bounds__(256)
void loss_reduce_kernel(const float* __restrict__ loss_rows, float* __restrict__ out) {
  const int tid = threadIdx.x;
  float s = 0.f;
  for (int j = 0; j < BTn/256; ++j) s += loss_rows[tid + j*256];
  __shared__ float red[256];
  red[tid] = s; __syncthreads();
  for (int st = 128; st > 0; st >>= 1) {
    if (tid < st) red[tid] += red[tid+st];
    __syncthreads();
  }
  if (tid == 0) out[0] = red[0] * (1.f/(float)BTn);
}

// =====================================================================================
extern "C" void kernel_launch(void* const* d_in, const int* in_sizes, int n_in,
                              void* d_out, int out_size, void* d_ws, size_t ws_size,
                              hipStream_t stream) {
  const int*   x       = (const int*)  d_in[0];
  const int*   y       = (const int*)  d_in[1];
  const float* wordemb = (const float*)d_in[2];
  const float* posemb  = (const float*)d_in[3];
  const float* Wq      = (const float*)d_in[4];
  const float* Wk      = (const float*)d_in[5];
  const float* Wv      = (const float*)d_in[6];
  const float* Wo      = (const float*)d_in[7];
  const float* bo      = (const float*)d_in[8];
  const float* ln1_g   = (const float*)d_in[9];
  const float* ln1_b   = (const float*)d_in[10];
  const float* W1      = (const float*)d_in[11];
  const float* b1      = (const float*)d_in[12];
  const float* W2      = (const float*)d_in[13];
  const float* b2      = (const float*)d_in[14];
  const float* ln2_g   = (const float*)d_in[15];
  const float* ln2_b   = (const float*)d_in[16];
  const float* Wl      = (const float*)d_in[17];
  const float* bl      = (const float*)d_in[18];

  char* ws = (char*)d_ws;
  size_t off = 0;
  auto alloc = [&](size_t bytes) -> char* {
    char* p = ws + off;
    off += (bytes + 255) & ~(size_t)255;
    return p;
  };
  unsigned short* wqkvT = (unsigned short*)alloc((size_t)Dn*2304*768*2);
  unsigned short* woT   = (unsigned short*)alloc((size_t)Dn*768*768*2);
  unsigned short* w1T   = (unsigned short*)alloc((size_t)Dn*3072*768*2);
  unsigned short* w2T   = (unsigned short*)alloc((size_t)Dn*768*3072*2);
  unsigned short* wlT   = (unsigned short*)alloc((size_t)Vn*768*2);
  float*          h     = (float*)alloc((size_t)BTn*Cn*4);
  unsigned short* hb    = (unsigned short*)alloc((size_t)BTn*Cn*2);
  unsigned short* qkvb  = (unsigned short*)alloc((size_t)BTn*3072*2);  // also ff1b alias
  unsigned short* vTb   = (unsigned short*)alloc((size_t)Bn*Hn*64*Tn*2);
  unsigned short* attb  = (unsigned short*)alloc((size_t)BTn*Cn*2);
  float*          tmp   = (float*)alloc((size_t)BTn*Cn*4);       // attout / ff2
  float*          loss_rows = (float*)alloc((size_t)BTn*4);
  unsigned short* ff1b  = qkvb;  // alias: qkv dead once attn done

  dim3 tb(32, 8);
  for (int d = 0; d < Dn; ++d) {
    transpose_bf16_kernel<<<dim3(24,24), tb, 0, stream>>>(Wq + (size_t)d*Cn*Cn, wqkvT + (size_t)d*2304*768,            Cn, Cn);
    transpose_bf16_kernel<<<dim3(24,24), tb, 0, stream>>>(Wk + (size_t)d*Cn*Cn, wqkvT + (size_t)d*2304*768 + 768*768,  Cn, Cn);
    transpose_bf16_kernel<<<dim3(24,24), tb, 0, stream>>>(Wv + (size_t)d*Cn*Cn, wqkvT + (size_t)d*2304*768 + 1536*768, Cn, Cn);
    transpose_bf16_kernel<<<dim3(24,24), tb, 0, stream>>>(Wo + (size_t)d*Cn*Cn, woT + (size_t)d*768*768,  Cn, Cn);
    transpose_bf16_kernel<<<dim3(96,24), tb, 0, stream>>>(W1 + (size_t)d*768*3072, w1T + (size_t)d*3072*768, 768, 3072);
    transpose_bf16_kernel<<<dim3(24,96), tb, 0, stream>>>(W2 + (size_t)d*3072*768, w2T + (size_t)d*768*3072, 3072, 768);
  }
  transpose_bf16_kernel<<<dim3(1000,24), tb, 0, stream>>>(Wl, wlT, 768, Vn);

  embed_kernel<<<(BTn*Cn/4)/256, 256, 0, stream>>>(x, wordemb, posemb, h, hb);

  for (int d = 0; d < Dn; ++d) {
    gemm_bf16_kernel<<<dim3(2304/128, BTn/128), 256, 0, stream>>>(
        hb, wqkvT + (size_t)d*2304*768, nullptr, nullptr, qkvb, BTn, 2304, 768, 0);
    vT_kernel<<<dim3(Tn/64, Hn, Bn), 256, 0, stream>>>(qkvb, vTb);
    attn_mfma_kernel<<<dim3(Tn/64, Hn, Bn), 256, 0, stream>>>(qkvb, vTb, attb);
    gemm_bf16_kernel<<<dim3(768/128, BTn/128), 256, 0, stream>>>(
        attb, woT + (size_t)d*768*768, bo + (size_t)d*768, tmp, nullptr, BTn, 768, 768, 0);
    ln_res_kernel<<<BTn, 256, 0, stream>>>(tmp, h, hb, ln1_g + (size_t)d*768, ln1_b + (size_t)d*768);
    gemm_bf16_kernel<<<dim3(3072/128, BTn/128), 256, 0, stream>>>(
        hb, w1T + (size_t)d*3072*768, b1 + (size_t)d*3072, nullptr, ff1b, BTn, 3072, 768, 1);
    gemm_bf16_kernel<<<dim3(768/128, BTn/128), 256, 0, stream>>>(
        ff1b, w2T + (size_t)d*768*3072, b2 + (size_t)d*768, tmp, nullptr, BTn, 768, 3072, 0);
    ln_res_kernel<<<BTn, 256, 0, stream>>>(tmp, h, hb, ln2_g + (size_t)d*768, ln2_b + (size_t)d*768);
  }

  float* logits = (float*)d_out;
  gemm_bf16_kernel<<<dim3(Vn/128, BTn/128), 256, 0, stream>>>(
      hb, wlT, bl, logits, nullptr, BTn, Vn, 768, 0);
  loss_row_kernel<<<BTn, 256, 0, stream>>>(logits, y, loss_rows);
  loss_reduce_kernel<<<1, 256, 0, stream>>>(loss_rows, logits + (size_t)BTn*Vn);
}